// Round 4
// baseline (12667.347 us; speedup 1.0000x reference)
//
#include <hip/hip_runtime.h>
#include <hip/hip_fp16.h>
#include <stdint.h>

#define N_NODES 20000
#define T_STEPS 16
#define F_INPUT 65
#define F_DIM   64
#define HID     128
#define LAT     64
#define N_EDGES 320000

typedef _Float16 f16x8 __attribute__((ext_vector_type(8)));
typedef float f32x4 __attribute__((ext_vector_type(4)));

__device__ __forceinline__ float rcp_fast(float x){ return __builtin_amdgcn_rcpf(x); }
__device__ __forceinline__ float sigm(float x){ return rcp_fast(1.0f + __expf(-x)); }
__device__ __forceinline__ float tanh_fast(float x){
  float e = __expf(2.0f * x);
  return 1.0f - 2.0f * rcp_fast(e + 1.0f);
}

// ---------------- graph prep ----------------
__global__ void k_zero(int* deg, float* h1, float* c1){
  int i = blockIdx.x * 256 + threadIdx.x;
  if (i < N_NODES) deg[i] = 0;
  const int tot = N_NODES * LAT;
  for (int idx = i; idx < tot; idx += gridDim.x * 256){ h1[idx] = 0.f; c1[idx] = 0.f; }
}

__global__ void k_count(const int* __restrict__ ei, int* __restrict__ deg){
  int e = blockIdx.x * 256 + threadIdx.x;
  if (e < N_EDGES) atomicAdd(&deg[ei[N_EDGES + e]], 1);
}

__global__ void k_dinv(const int* __restrict__ deg, float* __restrict__ dinv){
  int n = blockIdx.x * 256 + threadIdx.x;
  if (n < N_NODES) dinv[n] = rsqrtf((float)deg[n] + 1.0f);
}

__global__ void k_scan(const int* __restrict__ deg, int* __restrict__ offs){
  __shared__ int sbuf[1024];
  __shared__ int carry;
  int tid = threadIdx.x;
  if (tid == 0){ carry = 0; offs[0] = 0; }
  __syncthreads();
  for (int base = 0; base < N_NODES; base += 1024){
    int cb = carry;
    int v = (base + tid < N_NODES) ? deg[base + tid] : 0;
    sbuf[tid] = v;
    __syncthreads();
    for (int off = 1; off < 1024; off <<= 1){
      int add = (tid >= off) ? sbuf[tid - off] : 0;
      __syncthreads();
      sbuf[tid] += add;
      __syncthreads();
    }
    if (base + tid < N_NODES) offs[base + tid + 1] = cb + sbuf[tid];
    __syncthreads();
    if (tid == 1023) carry = cb + sbuf[1023];
    __syncthreads();
  }
}

__global__ void k_cursor(const int* __restrict__ offs, int* __restrict__ cursor){
  int n = blockIdx.x * 256 + threadIdx.x;
  if (n < N_NODES) cursor[n] = offs[n];
}

__global__ void k_fill(const int* __restrict__ ei, const float* __restrict__ dinv,
                       int* __restrict__ cursor, int* __restrict__ csrc,
                       float* __restrict__ cw){
  int e = blockIdx.x * 256 + threadIdx.x;
  if (e < N_EDGES){
    int s = ei[e], d = ei[N_EDGES + e];
    int p = atomicAdd(&cursor[d], 1);
    csrc[p] = s;
    cw[p] = dinv[s] * dinv[d];
  }
}

// xsw[n][t][k] = x[n][t][k] * x[n][t][64]
__global__ void k_xsw(const float* __restrict__ x, float* __restrict__ xsw){
  int idx = blockIdx.x * 256 + threadIdx.x;
  if (idx < N_NODES * T_STEPS * F_DIM){
    int nt = idx >> 6;
    int k = idx & 63;
    float imp = x[(size_t)nt * F_INPUT + F_DIM];
    xsw[idx] = x[(size_t)nt * F_INPUT + k] * imp;
  }
}

// ---------------- encoder: aggregate(64) -> project(128) -> LN -> henc[t][n][128]
__global__ __launch_bounds__(256) void k_enc(
    const float* __restrict__ xsw, const int* __restrict__ offs,
    const int* __restrict__ csrc, const float* __restrict__ cw,
    const float* __restrict__ dinv, const float* __restrict__ encW,
    const float* __restrict__ encb, const float* __restrict__ lng,
    const float* __restrict__ lnb, float* __restrict__ henc){
  __shared__ float Ws[64 * 128];
  __shared__ __align__(16) float us[16 * 64];
  __shared__ float hb[16 * 128];
  int n = blockIdx.x, tid = threadIdx.x;
  for (int i = tid; i < 64 * 128; i += 256) Ws[i] = encW[i];
  int t = tid >> 4, q = tid & 15;
  float a0 = 0.f, a1 = 0.f, a2 = 0.f, a3 = 0.f;
  int beg = offs[n], end = offs[n + 1];
  for (int e = beg; e < end; ++e){
    int s = csrc[e];
    float wv = cw[e];
    float4 v = *reinterpret_cast<const float4*>(&xsw[((size_t)(s * 16 + t)) * 64 + 4 * q]);
    a0 += wv * v.x; a1 += wv * v.y; a2 += wv * v.z; a3 += wv * v.w;
  }
  float di = dinv[n];
  float d2 = di * di;
  {
    float4 v = *reinterpret_cast<const float4*>(&xsw[((size_t)(n * 16 + t)) * 64 + 4 * q]);
    a0 += d2 * v.x; a1 += d2 * v.y; a2 += d2 * v.z; a3 += d2 * v.w;
  }
  us[t * 64 + 4 * q + 0] = a0;
  us[t * 64 + 4 * q + 1] = a1;
  us[t * 64 + 4 * q + 2] = a2;
  us[t * 64 + 4 * q + 3] = a3;
  __syncthreads();
  float acc[8];
  #pragma unroll
  for (int r = 0; r < 8; ++r) acc[r] = encb[q + 16 * r];
  for (int k = 0; k < 64; ++k){
    float uv = us[t * 64 + k];
    #pragma unroll
    for (int r = 0; r < 8; ++r) acc[r] += uv * Ws[k * 128 + q + 16 * r];
  }
  float s1 = 0.f, s2 = 0.f;
  #pragma unroll
  for (int r = 0; r < 8; ++r){ s1 += acc[r]; s2 += acc[r] * acc[r]; }
  #pragma unroll
  for (int m = 1; m < 16; m <<= 1){
    s1 += __shfl_xor(s1, m, 16);
    s2 += __shfl_xor(s2, m, 16);
  }
  float mean = s1 * (1.0f / 128.0f);
  float var = s2 * (1.0f / 128.0f) - mean * mean;
  float rstd = rsqrtf(var + 1e-5f);
  #pragma unroll
  for (int r = 0; r < 8; ++r){
    int j = q + 16 * r;
    hb[t * 128 + j] = (acc[r] - mean) * rstd * lng[j] + lnb[j];
  }
  __syncthreads();
  for (int i = tid; i < 2048; i += 256){
    int tt = i >> 7, j = i & 127;
    henc[((size_t)tt * N_NODES + n) * 128 + j] = hb[i];
  }
}

// ---------------- LSTM1: fused gemm + elementwise ----------------
__global__ __launch_bounds__(256) void k_l1step(
    const float* __restrict__ henc, float* __restrict__ h1, float* __restrict__ c1,
    const float* __restrict__ Wih, const float* __restrict__ Whh,
    const float* __restrict__ b, float* __restrict__ out0, int t){
  __shared__ __align__(16) char smem[32768];
  float* xt = (float*)smem;            // [192][36] phase 1
  float* gb = (float*)smem;            // [32][256] phase 2
  int tid = threadIdx.x;
  int n0 = blockIdx.x * 32;
  for (int i = tid; i < 32 * 128; i += 256){
    int ni = i >> 7, k = i & 127;
    xt[k * 36 + ni] = henc[((size_t)t * N_NODES + n0 + ni) * 128 + k];
  }
  for (int i = tid; i < 32 * 64; i += 256){
    int ni = i >> 6, k = i & 63;
    xt[(128 + k) * 36 + ni] = h1[(size_t)(n0 + ni) * 64 + k];
  }
  __syncthreads();
  int j = tid;
  float acc[32];
  #pragma unroll
  for (int m = 0; m < 32; ++m) acc[m] = 0.f;
  for (int k = 0; k < 128; ++k){
    float w = Wih[k * 256 + j];
    const float4* row = reinterpret_cast<const float4*>(&xt[k * 36]);
    #pragma unroll
    for (int m = 0; m < 8; ++m){
      float4 v = row[m];
      acc[4 * m + 0] += w * v.x; acc[4 * m + 1] += w * v.y;
      acc[4 * m + 2] += w * v.z; acc[4 * m + 3] += w * v.w;
    }
  }
  for (int k = 0; k < 64; ++k){
    float w = Whh[k * 256 + j];
    const float4* row = reinterpret_cast<const float4*>(&xt[(128 + k) * 36]);
    #pragma unroll
    for (int m = 0; m < 8; ++m){
      float4 v = row[m];
      acc[4 * m + 0] += w * v.x; acc[4 * m + 1] += w * v.y;
      acc[4 * m + 2] += w * v.z; acc[4 * m + 3] += w * v.w;
    }
  }
  float bj = b[j];
  __syncthreads();  // done reading xt
  for (int m = 0; m < 32; ++m) gb[m * 256 + j] = acc[m] + bj;
  __syncthreads();
  // phase 2: elementwise. thread -> (u, node-group)
  int u = tid & 63;
  int mg = tid >> 6;
  #pragma unroll
  for (int mm = 0; mm < 8; ++mm){
    int m = mg * 8 + mm;
    size_t idx = (size_t)(n0 + m) * 64 + u;
    float gi = gb[m * 256 + u], gf = gb[m * 256 + 64 + u];
    float gg = gb[m * 256 + 128 + u], go = gb[m * 256 + 192 + u];
    float c = sigm(gf) * c1[idx] + sigm(gi) * tanh_fast(gg);
    c1[idx] = c;
    float h = sigm(go) * tanh_fast(c);
    h1[idx] = h;
    out0[((size_t)(n0 + m) * 16 + t) * 64 + u] = h;
  }
}

// ---------------- LSTM2 prep ----------------
// B-fragment layout for mfma_f32_16x16x32_f16:
// WB2[((T*4+kt)*64 + lane)*8 + j] = Whh2[32*kt + 8*(lane>>4) + j][T*16 + (lane&15)]
__global__ void k_wprep2(const float* __restrict__ Whh2, __half* __restrict__ WB2){
  int idx = blockIdx.x * 256 + threadIdx.x;
  if (idx < 65536){
    int j = idx & 7;
    int lane = (idx >> 3) & 63;
    int kt = (idx >> 9) & 3;
    int T = idx >> 11;
    int k = 32 * kt + 8 * (lane >> 4) + j;
    int col = T * 16 + (lane & 15);
    WB2[idx] = __float2half(Whh2[k * 512 + col]);
  }
}

// Xp3[t][n][u][{i,g,f,o}] (halfs): pre-activation x-part of the 4 gates of unit u.
__global__ __launch_bounds__(256) void k_xp(
    const float* __restrict__ z, const float* __restrict__ Wih2,
    const float* __restrict__ b2, __half* __restrict__ Xp3){
  __shared__ __align__(16) float zt[64 * 20];
  int tid = threadIdx.x;
  int t = blockIdx.x / 1250;
  int n0 = (blockIdx.x % 1250) * 16;
  for (int i = tid; i < 16 * 64; i += 256){
    int ni = i >> 6, k = i & 63;
    zt[k * 20 + ni] = z[((size_t)(n0 + ni) * 16 + t) * 64 + k];
  }
  __syncthreads();
  int j = tid;                 // gate j and gate j+256
  float a0[16], a1[16];
  #pragma unroll
  for (int m = 0; m < 16; ++m){ a0[m] = 0.f; a1[m] = 0.f; }
  for (int k = 0; k < 64; ++k){
    float w0 = Wih2[k * 512 + j];
    float w1 = Wih2[k * 512 + 256 + j];
    const float4* row = reinterpret_cast<const float4*>(&zt[k * 20]);
    #pragma unroll
    for (int m = 0; m < 4; ++m){
      float4 v = row[m];
      a0[4 * m + 0] += w0 * v.x; a0[4 * m + 1] += w0 * v.y;
      a0[4 * m + 2] += w0 * v.z; a0[4 * m + 3] += w0 * v.w;
      a1[4 * m + 0] += w1 * v.x; a1[4 * m + 1] += w1 * v.y;
      a1[4 * m + 2] += w1 * v.z; a1[4 * m + 3] += w1 * v.w;
    }
  }
  float bj0 = b2[j], bj1 = b2[256 + j];
  // j = tid < 128 -> (i,g) of unit tid;  tid >= 128 -> (f,o) of unit tid-128
  int u = tid & 127;
  int gsel = tid >> 7;  // 0: write halfs {0,1}=(i,g); 1: halfs {2,3}=(f,o)
  for (int m = 0; m < 16; ++m){
    size_t hoff = (((size_t)t * N_NODES + n0 + m) * 128 + u) * 4 + gsel * 2;
    __half2 p = __floats2half2_rn(a0[m] + bj0, a1[m] + bj1);
    *reinterpret_cast<__half2*>(Xp3 + hoff) = p;
  }
}

// ---------------- LSTM2 serial: 4 blocks x 4 chains, 4 waves, MFMA ----------------
// Wave w covers col-tiles {4*s2 + w : s2=0..7} = gates i,f,g,o of units u0=16w+q, u1=64+16w+q.
// h stored compactly: 4 rows (chains) x 128 f16, XOR-swizzled; A-row q aliases stored row q>>2
// (4-lane broadcast reads, garbage C-rows discarded via reg0-of-group-g selection).
__global__ __launch_bounds__(256, 1) void k_lstm2(
    const __half* __restrict__ Xp3, const __half* __restrict__ WB2,
    float* __restrict__ hd){
  __shared__ __align__(16) char hls[2][1024];  // [buf][4 chains][128 f16]
  const int tid = threadIdx.x;
  const int w = tid >> 6;        // wave 0..3
  const int lane = tid & 63;
  const int q = lane & 15;
  const int g = lane >> 4;       // A k-slice group AND chain owned at C reg0 (row 4g)
  const int t = blockIdx.x * 4 + g;
  const int u0 = 16 * w + q;
  const int u1 = 64 + 16 * w + q;

  // B fragments: tile(s2) = 4*s2 + w, s2 = {i0,i1,f0,f1,g0,g1,o0,o1}
  f16x8 wb[8][4];
  {
    const f16x8* WBp = (const f16x8*)WB2;
    #pragma unroll
    for (int s2 = 0; s2 < 8; ++s2){
      #pragma unroll
      for (int kt = 0; kt < 4; ++kt){
        wb[s2][kt] = WBp[((4 * s2 + w) * 4 + kt) * 64 + lane];
      }
    }
  }

  // zero both h buffers
  for (int i = tid; i < 512; i += 256) ((int*)hls)[i] = 0;

  // A-read byte offsets: stored row r = q>>2, col bytes (64kt + 16g) ^ (r<<4)
  const int r_ = q >> 2;
  int rdoff[4];
  #pragma unroll
  for (int kt = 0; kt < 4; ++kt)
    rdoff[kt] = r_ * 256 + ((64 * kt + 16 * g) ^ (r_ << 4));
  // h write byte offsets: stored row g, col 2u ^ (g<<4)
  const int wr0 = g * 256 + ((2 * u0) ^ (g << 4));
  const int wr1 = g * 256 + ((2 * u1) ^ (g << 4));

  const __half* xpp0 = Xp3 + (((size_t)t * N_NODES) * 128 + u0) * 4;
  const __half* xpp1 = Xp3 + (((size_t)t * N_NODES) * 128 + u1) * 4;
  uint2 xa0 = *(const uint2*)(xpp0 + 0 * 512);
  uint2 xa1 = *(const uint2*)(xpp0 + 1 * 512);
  uint2 xa2 = *(const uint2*)(xpp0 + 2 * 512);
  uint2 xa3 = *(const uint2*)(xpp0 + 3 * 512);
  uint2 xb0 = *(const uint2*)(xpp1 + 0 * 512);
  uint2 xb1 = *(const uint2*)(xpp1 + 1 * 512);
  uint2 xb2 = *(const uint2*)(xpp1 + 2 * 512);
  uint2 xb3 = *(const uint2*)(xpp1 + 3 * 512);

  float c0 = 0.f, c1 = 0.f;
  float* hdp0 = hd + (size_t)t * 128 + u0;   // + n*2048 per step
  float* hdp1 = hd + (size_t)t * 128 + u1;
  __syncthreads();

#define L2_STEP(NN, CUR, XA, XB)                                               \
  {                                                                            \
    const char* rb = hls[CUR];                                                 \
    f16x8 a0 = *(const f16x8*)(rb + rdoff[0]);                                 \
    f16x8 a1 = *(const f16x8*)(rb + rdoff[1]);                                 \
    f16x8 a2 = *(const f16x8*)(rb + rdoff[2]);                                 \
    f16x8 a3 = *(const f16x8*)(rb + rdoff[3]);                                 \
    f32x4 acc[8];                                                              \
    _Pragma("unroll")                                                          \
    for (int s2 = 0; s2 < 8; ++s2) acc[s2] = (f32x4){0.f, 0.f, 0.f, 0.f};      \
    _Pragma("unroll")                                                          \
    for (int s2 = 0; s2 < 8; ++s2)                                             \
      acc[s2] = __builtin_amdgcn_mfma_f32_16x16x32_f16(a0, wb[s2][0], acc[s2], 0,0,0); \
    _Pragma("unroll")                                                          \
    for (int s2 = 0; s2 < 8; ++s2)                                             \
      acc[s2] = __builtin_amdgcn_mfma_f32_16x16x32_f16(a1, wb[s2][1], acc[s2], 0,0,0); \
    _Pragma("unroll")                                                          \
    for (int s2 = 0; s2 < 8; ++s2)                                             \
      acc[s2] = __builtin_amdgcn_mfma_f32_16x16x32_f16(a2, wb[s2][2], acc[s2], 0,0,0); \
    _Pragma("unroll")                                                          \
    for (int s2 = 0; s2 < 8; ++s2)                                             \
      acc[s2] = __builtin_amdgcn_mfma_f32_16x16x32_f16(a3, wb[s2][3], acc[s2], 0,0,0); \
    float gi0 = acc[0][0], gi1 = acc[1][0];                                    \
    float gf0 = acc[2][0], gf1 = acc[3][0];                                    \
    float gg0 = acc[4][0], gg1 = acc[5][0];                                    \
    float go0 = acc[6][0], go1 = acc[7][0];                                    \
    __half2 pig0 = __builtin_bit_cast(__half2, (XA).x);                        \
    __half2 pfo0 = __builtin_bit_cast(__half2, (XA).y);                        \
    __half2 pig1 = __builtin_bit_cast(__half2, (XB).x);                        \
    __half2 pfo1 = __builtin_bit_cast(__half2, (XB).y);                        \
    gi0 += __half2float(pig0.x); gg0 += __half2float(pig0.y);                  \
    gf0 += __half2float(pfo0.x); go0 += __half2float(pfo0.y);                  \
    gi1 += __half2float(pig1.x); gg1 += __half2float(pig1.y);                  \
    gf1 += __half2float(pfo1.x); go1 += __half2float(pfo1.y);                  \
    float ei0 = __expf(-gi0), eg0 = __expf(2.f * gg0);                         \
    float ei1 = __expf(-gi1), eg1 = __expf(2.f * gg1);                         \
    float rp0 = rcp_fast((1.f + ei0) * (eg0 + 1.f));                           \
    float rp1 = rcp_fast((1.f + ei1) * (eg1 + 1.f));                           \
    float pv0 = (eg0 - 1.f) * rp0;                                             \
    float pv1 = (eg1 - 1.f) * rp1;                                             \
    float ef0 = __expf(-gf0), ef1 = __expf(-gf1);                              \
    float fs0 = rcp_fast(1.f + ef0), fs1 = rcp_fast(1.f + ef1);                \
    c0 = fs0 * c0 + pv0;                                                       \
    c1 = fs1 * c1 + pv1;                                                       \
    float eo0 = __expf(-go0), ec0 = __expf(2.f * c0);                          \
    float eo1 = __expf(-go1), ec1 = __expf(2.f * c1);                          \
    float r20 = rcp_fast((1.f + eo0) * (ec0 + 1.f));                           \
    float r21 = rcp_fast((1.f + eo1) * (ec1 + 1.f));                           \
    float h0 = (ec0 - 1.f) * r20;                                              \
    float h1 = (ec1 - 1.f) * r21;                                              \
    hdp0[(size_t)(NN) * 2048] = h0;                                            \
    hdp1[(size_t)(NN) * 2048] = h1;                                            \
    *(_Float16*)(hls[CUR ^ 1] + wr0) = (_Float16)h0;                           \
    *(_Float16*)(hls[CUR ^ 1] + wr1) = (_Float16)h1;                           \
    __builtin_amdgcn_sched_barrier(0);                                         \
    asm volatile("s_waitcnt lgkmcnt(0)" ::: "memory");                         \
    __builtin_amdgcn_s_barrier();                                              \
    __builtin_amdgcn_sched_barrier(0);                                         \
  }

  for (int n = 0; n < N_NODES; n += 4){
    L2_STEP(n, 0, xa0, xb0);
    if (n + 4 < N_NODES){
      xa0 = *(const uint2*)(xpp0 + (size_t)(n + 4) * 512);
      xb0 = *(const uint2*)(xpp1 + (size_t)(n + 4) * 512);
    }
    L2_STEP(n + 1, 1, xa1, xb1);
    if (n + 5 < N_NODES){
      xa1 = *(const uint2*)(xpp0 + (size_t)(n + 5) * 512);
      xb1 = *(const uint2*)(xpp1 + (size_t)(n + 5) * 512);
    }
    L2_STEP(n + 2, 0, xa2, xb2);
    if (n + 6 < N_NODES){
      xa2 = *(const uint2*)(xpp0 + (size_t)(n + 6) * 512);
      xb2 = *(const uint2*)(xpp1 + (size_t)(n + 6) * 512);
    }
    L2_STEP(n + 3, 1, xa3, xb3);
    if (n + 7 < N_NODES){
      xa3 = *(const uint2*)(xpp0 + (size_t)(n + 7) * 512);
      xb3 = *(const uint2*)(xpp1 + (size_t)(n + 7) * 512);
    }
  }
#undef L2_STEP
}

// ---------------- decoder ----------------
__global__ __launch_bounds__(256) void k_decproj(
    const float* __restrict__ hd, const float* __restrict__ decW,
    const float* __restrict__ lng, const float* __restrict__ lnb,
    float* __restrict__ y){
  __shared__ float Ws[128 * 64];
  __shared__ float xr[16 * 128];
  int n = blockIdx.x, tid = threadIdx.x;
  for (int i = tid; i < 128 * 64; i += 256) Ws[i] = decW[i];
  for (int i = tid; i < 2048; i += 256) xr[i] = hd[(size_t)n * 2048 + i];
  __syncthreads();
  int t = tid >> 4, q = tid & 15;
  float v[8];
  float s1 = 0.f, s2 = 0.f;
  #pragma unroll
  for (int r = 0; r < 8; ++r){
    v[r] = xr[t * 128 + q + 16 * r];
    s1 += v[r]; s2 += v[r] * v[r];
  }
  #pragma unroll
  for (int m = 1; m < 16; m <<= 1){
    s1 += __shfl_xor(s1, m, 16);
    s2 += __shfl_xor(s2, m, 16);
  }
  float mean = s1 * (1.0f / 128.0f);
  float var = s2 * (1.0f / 128.0f) - mean * mean;
  float rstd = rsqrtf(var + 1e-5f);
  #pragma unroll
  for (int r = 0; r < 8; ++r){
    int jj = q + 16 * r;
    xr[t * 128 + jj] = (v[r] - mean) * rstd * lng[jj] + lnb[jj];
  }
  __syncthreads();
  float acc[4] = {0.f, 0.f, 0.f, 0.f};
  for (int k = 0; k < 128; ++k){
    float uv = xr[t * 128 + k];
    #pragma unroll
    for (int r = 0; r < 4; ++r) acc[r] += uv * Ws[k * 64 + q + 16 * r];
  }
  #pragma unroll
  for (int r = 0; r < 4; ++r)
    y[((size_t)n * 16 + t) * 64 + q + 16 * r] = acc[r];
}

__global__ __launch_bounds__(256) void k_decagg(
    const float* __restrict__ y, const int* __restrict__ offs,
    const int* __restrict__ csrc, const float* __restrict__ cw,
    const float* __restrict__ dinv, const float* __restrict__ decb,
    const float* __restrict__ x, float* __restrict__ out1){
  int n = blockIdx.x, tid = threadIdx.x;
  int t = tid >> 4, q = tid & 15;
  float a0 = 0.f, a1 = 0.f, a2 = 0.f, a3 = 0.f;
  int beg = offs[n], end = offs[n + 1];
  for (int e = beg; e < end; ++e){
    int s = csrc[e];
    float wv = cw[e];
    float4 v = *reinterpret_cast<const float4*>(&y[((size_t)(s * 16 + t)) * 64 + 4 * q]);
    a0 += wv * v.x; a1 += wv * v.y; a2 += wv * v.z; a3 += wv * v.w;
  }
  float di = dinv[n];
  float d2 = di * di;
  {
    float4 v = *reinterpret_cast<const float4*>(&y[((size_t)(n * 16 + t)) * 64 + 4 * q]);
    a0 += d2 * v.x; a1 += d2 * v.y; a2 += d2 * v.z; a3 += d2 * v.w;
  }
  a0 += decb[4 * q + 0]; a1 += decb[4 * q + 1];
  a2 += decb[4 * q + 2]; a3 += decb[4 * q + 3];
  size_t ob = ((size_t)n * 16 + t) * 65;
  out1[ob + 4 * q + 0] = a0;
  out1[ob + 4 * q + 1] = a1;
  out1[ob + 4 * q + 2] = a2;
  out1[ob + 4 * q + 3] = a3;
  if (q == 0) out1[ob + 64] = x[((size_t)n * 16 + t) * 65 + 64];
}

// ---------------- launch ----------------
extern "C" void kernel_launch(void* const* d_in, const int* in_sizes, int n_in,
                              void* d_out, int out_size, void* d_ws, size_t ws_size,
                              hipStream_t stream){
  (void)in_sizes; (void)n_in; (void)out_size; (void)ws_size;
  const float* x     = (const float*)d_in[0];
  const float* encW  = (const float*)d_in[1];
  const float* encb  = (const float*)d_in[2];
  const float* encg  = (const float*)d_in[3];
  const float* encbl = (const float*)d_in[4];
  const float* W1ih  = (const float*)d_in[5];
  const float* W1hh  = (const float*)d_in[6];
  const float* b1    = (const float*)d_in[7];
  const float* W2ih  = (const float*)d_in[8];
  const float* W2hh  = (const float*)d_in[9];
  const float* b2    = (const float*)d_in[10];
  const float* dlg   = (const float*)d_in[11];
  const float* dlb   = (const float*)d_in[12];
  const float* decW  = (const float*)d_in[13];
  const float* decb  = (const float*)d_in[14];
  const int*   ei    = (const int*)d_in[15];

  char* w = (char*)d_ws;
  auto alloc = [&](size_t bytes) -> char* {
    char* p = w;
    w += (bytes + 255) & ~(size_t)255;
    return p;
  };
  int*   deg    = (int*)  alloc((size_t)N_NODES * 4);
  float* dinv   = (float*)alloc((size_t)N_NODES * 4);
  int*   offs   = (int*)  alloc((size_t)(N_NODES + 1) * 4);
  int*   cursor = (int*)  alloc((size_t)N_NODES * 4);
  int*   csrc   = (int*)  alloc((size_t)N_EDGES * 4);
  float* cwt    = (float*)alloc((size_t)N_EDGES * 4);
  float* xsw    = (float*)alloc((size_t)N_NODES * T_STEPS * 64 * 4);  // later reused as y
  float* henc   = (float*)alloc((size_t)T_STEPS * N_NODES * 128 * 4); // later reused as hd
  float* h1     = (float*)alloc((size_t)N_NODES * 64 * 4);
  float* c1     = (float*)alloc((size_t)N_NODES * 64 * 4);
  __half* Xp3   = (__half*)alloc((size_t)T_STEPS * N_NODES * 512 * 2);
  __half* WB2   = (__half*)alloc((size_t)65536 * 2);

  float* out0 = (float*)d_out;
  float* out1 = out0 + (size_t)N_NODES * T_STEPS * 64;

  k_zero<<<5000, 256, 0, stream>>>(deg, h1, c1);
  k_count<<<(N_EDGES + 255) / 256, 256, 0, stream>>>(ei, deg);
  k_dinv<<<(N_NODES + 255) / 256, 256, 0, stream>>>(deg, dinv);
  k_scan<<<1, 1024, 0, stream>>>(deg, offs);
  k_cursor<<<(N_NODES + 255) / 256, 256, 0, stream>>>(offs, cursor);
  k_fill<<<(N_EDGES + 255) / 256, 256, 0, stream>>>(ei, dinv, cursor, csrc, cwt);
  k_xsw<<<(N_NODES * T_STEPS * 64 + 255) / 256, 256, 0, stream>>>(x, xsw);
  k_enc<<<N_NODES, 256, 0, stream>>>(xsw, offs, csrc, cwt, dinv, encW, encb, encg, encbl, henc);
  for (int t = 0; t < T_STEPS; ++t){
    k_l1step<<<625, 256, 0, stream>>>(henc, h1, c1, W1ih, W1hh, b1, out0, t);
  }
  k_wprep2<<<256, 256, 0, stream>>>(W2hh, WB2);
  k_xp<<<20000, 256, 0, stream>>>(out0, W2ih, b2, Xp3);
  k_lstm2<<<4, 256, 0, stream>>>(Xp3, WB2, henc);
  k_decproj<<<N_NODES, 256, 0, stream>>>(henc, decW, dlg, dlb, xsw);
  k_decagg<<<N_NODES, 256, 0, stream>>>(xsw, offs, csrc, cwt, dinv, decb, x, out1);
}

// Round 5
// 10700.767 us; speedup vs baseline: 1.1838x; 1.1838x over previous
//
#include <hip/hip_runtime.h>
#include <hip/hip_fp16.h>
#include <stdint.h>

#define N_NODES 20000
#define T_STEPS 16
#define F_INPUT 65
#define F_DIM   64
#define HID     128
#define LAT     64
#define N_EDGES 320000

typedef _Float16 f16x8 __attribute__((ext_vector_type(8)));
typedef float f32x4 __attribute__((ext_vector_type(4)));

__device__ __forceinline__ float rcp_fast(float x){ return __builtin_amdgcn_rcpf(x); }
__device__ __forceinline__ float sigm(float x){ return rcp_fast(1.0f + __expf(-x)); }
__device__ __forceinline__ float tanh_fast(float x){
  float e = __expf(2.0f * x);
  return 1.0f - 2.0f * rcp_fast(e + 1.0f);
}

// ---------------- graph prep ----------------
__global__ void k_zero(int* deg, float* h1, float* c1){
  int i = blockIdx.x * 256 + threadIdx.x;
  if (i < N_NODES) deg[i] = 0;
  const int tot = N_NODES * LAT;
  for (int idx = i; idx < tot; idx += gridDim.x * 256){ h1[idx] = 0.f; c1[idx] = 0.f; }
}

__global__ void k_count(const int* __restrict__ ei, int* __restrict__ deg){
  int e = blockIdx.x * 256 + threadIdx.x;
  if (e < N_EDGES) atomicAdd(&deg[ei[N_EDGES + e]], 1);
}

__global__ void k_dinv(const int* __restrict__ deg, float* __restrict__ dinv){
  int n = blockIdx.x * 256 + threadIdx.x;
  if (n < N_NODES) dinv[n] = rsqrtf((float)deg[n] + 1.0f);
}

__global__ void k_scan(const int* __restrict__ deg, int* __restrict__ offs){
  __shared__ int sbuf[1024];
  __shared__ int carry;
  int tid = threadIdx.x;
  if (tid == 0){ carry = 0; offs[0] = 0; }
  __syncthreads();
  for (int base = 0; base < N_NODES; base += 1024){
    int cb = carry;
    int v = (base + tid < N_NODES) ? deg[base + tid] : 0;
    sbuf[tid] = v;
    __syncthreads();
    for (int off = 1; off < 1024; off <<= 1){
      int add = (tid >= off) ? sbuf[tid - off] : 0;
      __syncthreads();
      sbuf[tid] += add;
      __syncthreads();
    }
    if (base + tid < N_NODES) offs[base + tid + 1] = cb + sbuf[tid];
    __syncthreads();
    if (tid == 1023) carry = cb + sbuf[1023];
    __syncthreads();
  }
}

__global__ void k_cursor(const int* __restrict__ offs, int* __restrict__ cursor){
  int n = blockIdx.x * 256 + threadIdx.x;
  if (n < N_NODES) cursor[n] = offs[n];
}

__global__ void k_fill(const int* __restrict__ ei, const float* __restrict__ dinv,
                       int* __restrict__ cursor, int* __restrict__ csrc,
                       float* __restrict__ cw){
  int e = blockIdx.x * 256 + threadIdx.x;
  if (e < N_EDGES){
    int s = ei[e], d = ei[N_EDGES + e];
    int p = atomicAdd(&cursor[d], 1);
    csrc[p] = s;
    cw[p] = dinv[s] * dinv[d];
  }
}

// xsw[n][t][k] = x[n][t][k] * x[n][t][64]
__global__ void k_xsw(const float* __restrict__ x, float* __restrict__ xsw){
  int idx = blockIdx.x * 256 + threadIdx.x;
  if (idx < N_NODES * T_STEPS * F_DIM){
    int nt = idx >> 6;
    int k = idx & 63;
    float imp = x[(size_t)nt * F_INPUT + F_DIM];
    xsw[idx] = x[(size_t)nt * F_INPUT + k] * imp;
  }
}

// ---------------- encoder: aggregate(64) -> project(128) -> LN -> henc[t][n][128]
__global__ __launch_bounds__(256) void k_enc(
    const float* __restrict__ xsw, const int* __restrict__ offs,
    const int* __restrict__ csrc, const float* __restrict__ cw,
    const float* __restrict__ dinv, const float* __restrict__ encW,
    const float* __restrict__ encb, const float* __restrict__ lng,
    const float* __restrict__ lnb, float* __restrict__ henc){
  __shared__ float Ws[64 * 128];
  __shared__ __align__(16) float us[16 * 64];
  __shared__ float hb[16 * 128];
  int n = blockIdx.x, tid = threadIdx.x;
  for (int i = tid; i < 64 * 128; i += 256) Ws[i] = encW[i];
  int t = tid >> 4, q = tid & 15;
  float a0 = 0.f, a1 = 0.f, a2 = 0.f, a3 = 0.f;
  int beg = offs[n], end = offs[n + 1];
  for (int e = beg; e < end; ++e){
    int s = csrc[e];
    float wv = cw[e];
    float4 v = *reinterpret_cast<const float4*>(&xsw[((size_t)(s * 16 + t)) * 64 + 4 * q]);
    a0 += wv * v.x; a1 += wv * v.y; a2 += wv * v.z; a3 += wv * v.w;
  }
  float di = dinv[n];
  float d2 = di * di;
  {
    float4 v = *reinterpret_cast<const float4*>(&xsw[((size_t)(n * 16 + t)) * 64 + 4 * q]);
    a0 += d2 * v.x; a1 += d2 * v.y; a2 += d2 * v.z; a3 += d2 * v.w;
  }
  us[t * 64 + 4 * q + 0] = a0;
  us[t * 64 + 4 * q + 1] = a1;
  us[t * 64 + 4 * q + 2] = a2;
  us[t * 64 + 4 * q + 3] = a3;
  __syncthreads();
  float acc[8];
  #pragma unroll
  for (int r = 0; r < 8; ++r) acc[r] = encb[q + 16 * r];
  for (int k = 0; k < 64; ++k){
    float uv = us[t * 64 + k];
    #pragma unroll
    for (int r = 0; r < 8; ++r) acc[r] += uv * Ws[k * 128 + q + 16 * r];
  }
  float s1 = 0.f, s2 = 0.f;
  #pragma unroll
  for (int r = 0; r < 8; ++r){ s1 += acc[r]; s2 += acc[r] * acc[r]; }
  #pragma unroll
  for (int m = 1; m < 16; m <<= 1){
    s1 += __shfl_xor(s1, m, 16);
    s2 += __shfl_xor(s2, m, 16);
  }
  float mean = s1 * (1.0f / 128.0f);
  float var = s2 * (1.0f / 128.0f) - mean * mean;
  float rstd = rsqrtf(var + 1e-5f);
  #pragma unroll
  for (int r = 0; r < 8; ++r){
    int j = q + 16 * r;
    hb[t * 128 + j] = (acc[r] - mean) * rstd * lng[j] + lnb[j];
  }
  __syncthreads();
  for (int i = tid; i < 2048; i += 256){
    int tt = i >> 7, j = i & 127;
    henc[((size_t)tt * N_NODES + n) * 128 + j] = hb[i];
  }
}

// ---------------- LSTM1: fused gemm + elementwise ----------------
__global__ __launch_bounds__(256) void k_l1step(
    const float* __restrict__ henc, float* __restrict__ h1, float* __restrict__ c1,
    const float* __restrict__ Wih, const float* __restrict__ Whh,
    const float* __restrict__ b, float* __restrict__ out0, int t){
  __shared__ __align__(16) char smem[32768];
  float* xt = (float*)smem;            // [192][36] phase 1
  float* gb = (float*)smem;            // [32][256] phase 2
  int tid = threadIdx.x;
  int n0 = blockIdx.x * 32;
  for (int i = tid; i < 32 * 128; i += 256){
    int ni = i >> 7, k = i & 127;
    xt[k * 36 + ni] = henc[((size_t)t * N_NODES + n0 + ni) * 128 + k];
  }
  for (int i = tid; i < 32 * 64; i += 256){
    int ni = i >> 6, k = i & 63;
    xt[(128 + k) * 36 + ni] = h1[(size_t)(n0 + ni) * 64 + k];
  }
  __syncthreads();
  int j = tid;
  float acc[32];
  #pragma unroll
  for (int m = 0; m < 32; ++m) acc[m] = 0.f;
  for (int k = 0; k < 128; ++k){
    float w = Wih[k * 256 + j];
    const float4* row = reinterpret_cast<const float4*>(&xt[k * 36]);
    #pragma unroll
    for (int m = 0; m < 8; ++m){
      float4 v = row[m];
      acc[4 * m + 0] += w * v.x; acc[4 * m + 1] += w * v.y;
      acc[4 * m + 2] += w * v.z; acc[4 * m + 3] += w * v.w;
    }
  }
  for (int k = 0; k < 64; ++k){
    float w = Whh[k * 256 + j];
    const float4* row = reinterpret_cast<const float4*>(&xt[(128 + k) * 36]);
    #pragma unroll
    for (int m = 0; m < 8; ++m){
      float4 v = row[m];
      acc[4 * m + 0] += w * v.x; acc[4 * m + 1] += w * v.y;
      acc[4 * m + 2] += w * v.z; acc[4 * m + 3] += w * v.w;
    }
  }
  float bj = b[j];
  __syncthreads();  // done reading xt
  for (int m = 0; m < 32; ++m) gb[m * 256 + j] = acc[m] + bj;
  __syncthreads();
  // phase 2: elementwise. thread -> (u, node-group)
  int u = tid & 63;
  int mg = tid >> 6;
  #pragma unroll
  for (int mm = 0; mm < 8; ++mm){
    int m = mg * 8 + mm;
    size_t idx = (size_t)(n0 + m) * 64 + u;
    float gi = gb[m * 256 + u], gf = gb[m * 256 + 64 + u];
    float gg = gb[m * 256 + 128 + u], go = gb[m * 256 + 192 + u];
    float c = sigm(gf) * c1[idx] + sigm(gi) * tanh_fast(gg);
    c1[idx] = c;
    float h = sigm(go) * tanh_fast(c);
    h1[idx] = h;
    out0[((size_t)(n0 + m) * 16 + t) * 64 + u] = h;
  }
}

// ---------------- LSTM2 prep ----------------
// B-fragment layout for mfma_f32_16x16x32_f16:
// WB2[((T*4+kt)*64 + lane)*8 + j] = Whh2[32*kt + 8*(lane>>4) + j][T*16 + (lane&15)]
__global__ void k_wprep2(const float* __restrict__ Whh2, __half* __restrict__ WB2){
  int idx = blockIdx.x * 256 + threadIdx.x;
  if (idx < 65536){
    int j = idx & 7;
    int lane = (idx >> 3) & 63;
    int kt = (idx >> 9) & 3;
    int T = idx >> 11;
    int k = 32 * kt + 8 * (lane >> 4) + j;
    int col = T * 16 + (lane & 15);
    WB2[idx] = __float2half(Whh2[k * 512 + col]);
  }
}

// Xp3[t][n][u][{i,g,f,o}] (halfs): pre-activation x-part of the 4 gates of unit u.
__global__ __launch_bounds__(256) void k_xp(
    const float* __restrict__ z, const float* __restrict__ Wih2,
    const float* __restrict__ b2, __half* __restrict__ Xp3){
  __shared__ __align__(16) float zt[64 * 20];
  int tid = threadIdx.x;
  int t = blockIdx.x / 1250;
  int n0 = (blockIdx.x % 1250) * 16;
  for (int i = tid; i < 16 * 64; i += 256){
    int ni = i >> 6, k = i & 63;
    zt[k * 20 + ni] = z[((size_t)(n0 + ni) * 16 + t) * 64 + k];
  }
  __syncthreads();
  int j = tid;                 // gate j and gate j+256
  float a0[16], a1[16];
  #pragma unroll
  for (int m = 0; m < 16; ++m){ a0[m] = 0.f; a1[m] = 0.f; }
  for (int k = 0; k < 64; ++k){
    float w0 = Wih2[k * 512 + j];
    float w1 = Wih2[k * 512 + 256 + j];
    const float4* row = reinterpret_cast<const float4*>(&zt[k * 20]);
    #pragma unroll
    for (int m = 0; m < 4; ++m){
      float4 v = row[m];
      a0[4 * m + 0] += w0 * v.x; a0[4 * m + 1] += w0 * v.y;
      a0[4 * m + 2] += w0 * v.z; a0[4 * m + 3] += w0 * v.w;
      a1[4 * m + 0] += w1 * v.x; a1[4 * m + 1] += w1 * v.y;
      a1[4 * m + 2] += w1 * v.z; a1[4 * m + 3] += w1 * v.w;
    }
  }
  float bj0 = b2[j], bj1 = b2[256 + j];
  // j = tid < 128 -> (i,g) of unit tid;  tid >= 128 -> (f,o) of unit tid-128
  int u = tid & 127;
  int gsel = tid >> 7;  // 0: write halfs {0,1}=(i,g); 1: halfs {2,3}=(f,o)
  for (int m = 0; m < 16; ++m){
    size_t hoff = (((size_t)t * N_NODES + n0 + m) * 128 + u) * 4 + gsel * 2;
    __half2 p = __floats2half2_rn(a0[m] + bj0, a1[m] + bj1);
    *reinterpret_cast<__half2*>(Xp3 + hoff) = p;
  }
}

// ---------------- LSTM2 serial: 4 blocks x 4 chains, 8 waves, MFMA ----------------
// Wave w covers col-tiles {gate*8 + w} -> lane (q,g) owns unit u=16w+q of chain g.
// h stored compactly: 4 rows (chains) x 272 B (128 f16 + 16 B pad) -> conflict-free
// broadcast reads (row q>>2; 4 disjoint bank quads per subphase) and 2-way-free writes.
__global__ __launch_bounds__(512, 1) void k_lstm2(
    const __half* __restrict__ Xp3, const __half* __restrict__ WB2,
    float* __restrict__ hd){
  __shared__ __align__(16) char hls[2][1088];  // [buf][4 chains][272 B]
  const int tid = threadIdx.x;
  const int w = tid >> 6;        // wave 0..7
  const int lane = tid & 63;
  const int q = lane & 15;
  const int g = lane >> 4;       // chain (valid C rows 4g..4g+3) and A k-slice group
  const int t = blockIdx.x * 4 + g;
  const int u = 16 * w + q;      // hidden unit owned by this lane

  // B fragments: tile(gate) = gate*8 + w, gate order {i,f,g,o}
  f16x8 wb[4][4];
  {
    const f16x8* WBp = (const f16x8*)WB2;
    #pragma unroll
    for (int gate = 0; gate < 4; ++gate){
      #pragma unroll
      for (int kt = 0; kt < 4; ++kt){
        wb[gate][kt] = WBp[((gate * 8 + w) * 4 + kt) * 64 + lane];
      }
    }
  }

  // zero both h buffers (2*1088 B = 544 ints)
  for (int i = tid; i < 544; i += 512) ((int*)hls)[i] = 0;

  // A-read byte offsets: stored row r = q>>2 (chain), bytes 16g + 64kt within row
  const int r_ = q >> 2;
  int rdoff[4];
  #pragma unroll
  for (int kt = 0; kt < 4; ++kt)
    rdoff[kt] = r_ * 272 + 16 * g + 64 * kt;
  // h write byte offset: stored row g (own chain), col u
  const int wroff = g * 272 + 2 * u;

  const __half* xpp = Xp3 + (((size_t)t * N_NODES) * 128 + u) * 4;
  uint2 xa0 = *(const uint2*)(xpp + 0 * 512);
  uint2 xa1 = *(const uint2*)(xpp + 1 * 512);
  uint2 xa2 = *(const uint2*)(xpp + 2 * 512);
  uint2 xa3 = *(const uint2*)(xpp + 3 * 512);

  float c = 0.f;
  float* hdp = hd + (size_t)t * 128 + u;   // + n*2048 per step
  __syncthreads();

#define L2_STEP(NN, CUR, XA)                                                   \
  {                                                                            \
    const char* rb = hls[CUR];                                                 \
    f16x8 a0 = *(const f16x8*)(rb + rdoff[0]);                                 \
    f16x8 a1 = *(const f16x8*)(rb + rdoff[1]);                                 \
    f16x8 a2 = *(const f16x8*)(rb + rdoff[2]);                                 \
    f16x8 a3 = *(const f16x8*)(rb + rdoff[3]);                                 \
    f32x4 acc[4];                                                              \
    _Pragma("unroll")                                                          \
    for (int gate = 0; gate < 4; ++gate) acc[gate] = (f32x4){0.f,0.f,0.f,0.f}; \
    _Pragma("unroll")                                                          \
    for (int gate = 0; gate < 4; ++gate)                                       \
      acc[gate] = __builtin_amdgcn_mfma_f32_16x16x32_f16(a0, wb[gate][0], acc[gate], 0,0,0); \
    _Pragma("unroll")                                                          \
    for (int gate = 0; gate < 4; ++gate)                                       \
      acc[gate] = __builtin_amdgcn_mfma_f32_16x16x32_f16(a1, wb[gate][1], acc[gate], 0,0,0); \
    _Pragma("unroll")                                                          \
    for (int gate = 0; gate < 4; ++gate)                                       \
      acc[gate] = __builtin_amdgcn_mfma_f32_16x16x32_f16(a2, wb[gate][2], acc[gate], 0,0,0); \
    _Pragma("unroll")                                                          \
    for (int gate = 0; gate < 4; ++gate)                                       \
      acc[gate] = __builtin_amdgcn_mfma_f32_16x16x32_f16(a3, wb[gate][3], acc[gate], 0,0,0); \
    __half2 pig = __builtin_bit_cast(__half2, (XA).x);                         \
    __half2 pfo = __builtin_bit_cast(__half2, (XA).y);                         \
    float gi = acc[0][0] + __half2float(pig.x);                                \
    float gf = acc[1][0] + __half2float(pfo.x);                                \
    float gg = acc[2][0] + __half2float(pig.y);                                \
    float go = acc[3][0] + __half2float(pfo.y);                                \
    float ei = __expf(-gi), ef = __expf(-gf);                                  \
    float eg = __expf(2.f * gg), eo = __expf(-go);                             \
    float pi1 = 1.f + ei, pf1 = 1.f + ef, pg1 = eg + 1.f;                      \
    float pig_ = pi1 * pg1;                                                    \
    float num = c * pig_ + (eg - 1.f) * pf1;                                   \
    c = num * rcp_fast(pf1 * pig_);                                            \
    float ec = __expf(2.f * c);                                                \
    float h = (ec - 1.f) * rcp_fast((1.f + eo) * (ec + 1.f));                  \
    hdp[(size_t)(NN) * 2048] = h;                                              \
    *(_Float16*)(hls[CUR ^ 1] + wroff) = (_Float16)h;                          \
    __builtin_amdgcn_sched_barrier(0);                                         \
    asm volatile("s_waitcnt lgkmcnt(0)" ::: "memory");                         \
    __builtin_amdgcn_s_barrier();                                              \
    __builtin_amdgcn_sched_barrier(0);                                         \
  }

  for (int n = 0; n < N_NODES; n += 4){
    L2_STEP(n, 0, xa0);
    if (n + 4 < N_NODES) xa0 = *(const uint2*)(xpp + (size_t)(n + 4) * 512);
    L2_STEP(n + 1, 1, xa1);
    if (n + 5 < N_NODES) xa1 = *(const uint2*)(xpp + (size_t)(n + 5) * 512);
    L2_STEP(n + 2, 0, xa2);
    if (n + 6 < N_NODES) xa2 = *(const uint2*)(xpp + (size_t)(n + 6) * 512);
    L2_STEP(n + 3, 1, xa3);
    if (n + 7 < N_NODES) xa3 = *(const uint2*)(xpp + (size_t)(n + 7) * 512);
  }
#undef L2_STEP
}

// ---------------- decoder ----------------
__global__ __launch_bounds__(256) void k_decproj(
    const float* __restrict__ hd, const float* __restrict__ decW,
    const float* __restrict__ lng, const float* __restrict__ lnb,
    float* __restrict__ y){
  __shared__ float Ws[128 * 64];
  __shared__ float xr[16 * 128];
  int n = blockIdx.x, tid = threadIdx.x;
  for (int i = tid; i < 128 * 64; i += 256) Ws[i] = decW[i];
  for (int i = tid; i < 2048; i += 256) xr[i] = hd[(size_t)n * 2048 + i];
  __syncthreads();
  int t = tid >> 4, q = tid & 15;
  float v[8];
  float s1 = 0.f, s2 = 0.f;
  #pragma unroll
  for (int r = 0; r < 8; ++r){
    v[r] = xr[t * 128 + q + 16 * r];
    s1 += v[r]; s2 += v[r] * v[r];
  }
  #pragma unroll
  for (int m = 1; m < 16; m <<= 1){
    s1 += __shfl_xor(s1, m, 16);
    s2 += __shfl_xor(s2, m, 16);
  }
  float mean = s1 * (1.0f / 128.0f);
  float var = s2 * (1.0f / 128.0f) - mean * mean;
  float rstd = rsqrtf(var + 1e-5f);
  #pragma unroll
  for (int r = 0; r < 8; ++r){
    int jj = q + 16 * r;
    xr[t * 128 + jj] = (v[r] - mean) * rstd * lng[jj] + lnb[jj];
  }
  __syncthreads();
  float acc[4] = {0.f, 0.f, 0.f, 0.f};
  for (int k = 0; k < 128; ++k){
    float uv = xr[t * 128 + k];
    #pragma unroll
    for (int r = 0; r < 4; ++r) acc[r] += uv * Ws[k * 64 + q + 16 * r];
  }
  #pragma unroll
  for (int r = 0; r < 4; ++r)
    y[((size_t)n * 16 + t) * 64 + q + 16 * r] = acc[r];
}

__global__ __launch_bounds__(256) void k_decagg(
    const float* __restrict__ y, const int* __restrict__ offs,
    const int* __restrict__ csrc, const float* __restrict__ cw,
    const float* __restrict__ dinv, const float* __restrict__ decb,
    const float* __restrict__ x, float* __restrict__ out1){
  int n = blockIdx.x, tid = threadIdx.x;
  int t = tid >> 4, q = tid & 15;
  float a0 = 0.f, a1 = 0.f, a2 = 0.f, a3 = 0.f;
  int beg = offs[n], end = offs[n + 1];
  for (int e = beg; e < end; ++e){
    int s = csrc[e];
    float wv = cw[e];
    float4 v = *reinterpret_cast<const float4*>(&y[((size_t)(s * 16 + t)) * 64 + 4 * q]);
    a0 += wv * v.x; a1 += wv * v.y; a2 += wv * v.z; a3 += wv * v.w;
  }
  float di = dinv[n];
  float d2 = di * di;
  {
    float4 v = *reinterpret_cast<const float4*>(&y[((size_t)(n * 16 + t)) * 64 + 4 * q]);
    a0 += d2 * v.x; a1 += d2 * v.y; a2 += d2 * v.z; a3 += d2 * v.w;
  }
  a0 += decb[4 * q + 0]; a1 += decb[4 * q + 1];
  a2 += decb[4 * q + 2]; a3 += decb[4 * q + 3];
  size_t ob = ((size_t)n * 16 + t) * 65;
  out1[ob + 4 * q + 0] = a0;
  out1[ob + 4 * q + 1] = a1;
  out1[ob + 4 * q + 2] = a2;
  out1[ob + 4 * q + 3] = a3;
  if (q == 0) out1[ob + 64] = x[((size_t)n * 16 + t) * 65 + 64];
}

// ---------------- launch ----------------
extern "C" void kernel_launch(void* const* d_in, const int* in_sizes, int n_in,
                              void* d_out, int out_size, void* d_ws, size_t ws_size,
                              hipStream_t stream){
  (void)in_sizes; (void)n_in; (void)out_size; (void)ws_size;
  const float* x     = (const float*)d_in[0];
  const float* encW  = (const float*)d_in[1];
  const float* encb  = (const float*)d_in[2];
  const float* encg  = (const float*)d_in[3];
  const float* encbl = (const float*)d_in[4];
  const float* W1ih  = (const float*)d_in[5];
  const float* W1hh  = (const float*)d_in[6];
  const float* b1    = (const float*)d_in[7];
  const float* W2ih  = (const float*)d_in[8];
  const float* W2hh  = (const float*)d_in[9];
  const float* b2    = (const float*)d_in[10];
  const float* dlg   = (const float*)d_in[11];
  const float* dlb   = (const float*)d_in[12];
  const float* decW  = (const float*)d_in[13];
  const float* decb  = (const float*)d_in[14];
  const int*   ei    = (const int*)d_in[15];

  char* w = (char*)d_ws;
  auto alloc = [&](size_t bytes) -> char* {
    char* p = w;
    w += (bytes + 255) & ~(size_t)255;
    return p;
  };
  int*   deg    = (int*)  alloc((size_t)N_NODES * 4);
  float* dinv   = (float*)alloc((size_t)N_NODES * 4);
  int*   offs   = (int*)  alloc((size_t)(N_NODES + 1) * 4);
  int*   cursor = (int*)  alloc((size_t)N_NODES * 4);
  int*   csrc   = (int*)  alloc((size_t)N_EDGES * 4);
  float* cwt    = (float*)alloc((size_t)N_EDGES * 4);
  float* xsw    = (float*)alloc((size_t)N_NODES * T_STEPS * 64 * 4);  // later reused as y
  float* henc   = (float*)alloc((size_t)T_STEPS * N_NODES * 128 * 4); // later reused as hd
  float* h1     = (float*)alloc((size_t)N_NODES * 64 * 4);
  float* c1     = (float*)alloc((size_t)N_NODES * 64 * 4);
  __half* Xp3   = (__half*)alloc((size_t)T_STEPS * N_NODES * 512 * 2);
  __half* WB2   = (__half*)alloc((size_t)65536 * 2);

  float* out0 = (float*)d_out;
  float* out1 = out0 + (size_t)N_NODES * T_STEPS * 64;

  k_zero<<<5000, 256, 0, stream>>>(deg, h1, c1);
  k_count<<<(N_EDGES + 255) / 256, 256, 0, stream>>>(ei, deg);
  k_dinv<<<(N_NODES + 255) / 256, 256, 0, stream>>>(deg, dinv);
  k_scan<<<1, 1024, 0, stream>>>(deg, offs);
  k_cursor<<<(N_NODES + 255) / 256, 256, 0, stream>>>(offs, cursor);
  k_fill<<<(N_EDGES + 255) / 256, 256, 0, stream>>>(ei, dinv, cursor, csrc, cwt);
  k_xsw<<<(N_NODES * T_STEPS * 64 + 255) / 256, 256, 0, stream>>>(x, xsw);
  k_enc<<<N_NODES, 256, 0, stream>>>(xsw, offs, csrc, cwt, dinv, encW, encb, encg, encbl, henc);
  for (int t = 0; t < T_STEPS; ++t){
    k_l1step<<<625, 256, 0, stream>>>(henc, h1, c1, W1ih, W1hh, b1, out0, t);
  }
  k_wprep2<<<256, 256, 0, stream>>>(W2hh, WB2);
  k_xp<<<20000, 256, 0, stream>>>(out0, W2ih, b2, Xp3);
  k_lstm2<<<4, 512, 0, stream>>>(Xp3, WB2, henc);
  k_decproj<<<N_NODES, 256, 0, stream>>>(henc, decW, dlg, dlb, xsw);
  k_decagg<<<N_NODES, 256, 0, stream>>>(xsw, offs, csrc, cwt, dinv, decb, x, out1);
}